// Round 10
// baseline (342.376 us; speedup 1.0000x reference)
//
#include <hip/hip_runtime.h>

#define HIDN 20
#define CHUNK 512
#define WARM 64
#define NB ((CHUNK + WARM) / 64)   // 9 batches of 64 steps
#define WARMB (WARM / 64)          // first batch is warmup

typedef float v2f __attribute__((ext_vector_type(2)));

// readlane -> wave-uniform SGPR float (for the scalar x inputs)
__device__ __forceinline__ float bcast(float v, int l) {
    return __int_as_float(__builtin_amdgcn_readlane(__float_as_int(v), l));
}
// full-wave broadcast via ds_bpermute (DS pipe; result is a VGPR usable
// directly as a v_pk_fma_f32 operand half -- no SGPR, no splat movs)
__device__ __forceinline__ float bperm(float v, int srcLane) {
    return __int_as_float(__builtin_amdgcn_ds_bpermute(srcLane << 2, __float_as_int(v)));
}
__device__ __forceinline__ v2f fma2(v2f a, v2f b, v2f c) {
    return __builtin_elementwise_fma(a, b, c);      // -> v_pk_fma_f32 (all-VGPR)
}

// gate-split LSTM cell epilogue (f32). Half A lanes hold gate pre-acts (i,f),
// half B lanes hold (g,o) for the same unit.
__device__ __forceinline__ float gate_update(float aA, float aB, float& c,
                                             float cA, float mA, float dA,
                                             bool hB) {
    const float cB = -1.4426950408889634f;
    const float cT =  2.8853900817779268f;
    float eA = __builtin_amdgcn_exp2f(cA * aA);
    float sA = __builtin_amdgcn_rcpf(1.0f + eA);
    float gA = __builtin_fmaf(mA, sA, -dA);          // i (half A) / g (half B)
    float eB = __builtin_amdgcn_exp2f(cB * aB);
    float gB = __builtin_amdgcn_rcpf(1.0f + eB);     // f (half A) / o (half B)
    float oA = __shfl_xor(gA, 32);
    float oB = __shfl_xor(gB, 32);
    float f = hB ? oB : gB;
    float o = hB ? gB : oB;
    c = __builtin_fmaf(f, c, gA * oA);
    float ec = __builtin_amdgcn_exp2f(cT * c);
    float tc = 1.0f - 2.0f * __builtin_amdgcn_rcpf(ec + 1.0f);
    return o * tc;
}

#define RJA(M) M(0) M(1) M(2) M(3) M(4)
#define RJB(M) M(5) M(6) M(7) M(8) M(9)
#define RJ(M) RJA(M) RJB(M)

// One 64-lane wave = one chunk of CHUNK steps (WARM discarded warmup steps).
// k-axis packing: weight pairs (W[row][2j],W[row][2j+1]) meet broadcast pairs
// (h_2j,h_2j+1) built once per step via ds_bpermute. All f32.
// waves_per_eu(1,1): full 512-reg unified budget -> ~210 live values fit in
// ARCH VGPRs, eliminating the AGPR-shuttle copies diagnosed in r6/r9.
__global__ __launch_bounds__(64)
__attribute__((amdgpu_waves_per_eu(1, 1)))
void lstm_opt_kernel(const float* __restrict__ grad, const float* __restrict__ par,
                     const float* __restrict__ Wih0, const float* __restrict__ Whh0,
                     const float* __restrict__ bih0, const float* __restrict__ bhh0,
                     const float* __restrict__ Wih1, const float* __restrict__ Whh1,
                     const float* __restrict__ bih1, const float* __restrict__ bhh1,
                     const float* __restrict__ Wout, const float* __restrict__ bout,
                     float* __restrict__ out, int n)
{
    const int lane  = threadIdx.x;
    const int lh    = lane & 31;
    const bool hB   = lane >= 32;
    const int u     = (lh < HIDN) ? lh : (HIDN - 1);
    const bool valid = (lh < HIDN);

    const int rowA = (hB ? 2 : 0) * HIDN + u;   // i-row or g-row
    const int rowB = (hB ? 3 : 1) * HIDN + u;   // f-row or o-row

    // ---- k-paired register weights (named v2f scalars; no arrays) ----
#define DECLW(j) v2f w0A_##j, w0B_##j, wiA_##j, wiB_##j, whA_##j, whB_##j;
    RJ(DECLW)
#undef DECLW
#define LOADW(j) \
    w0A_##j.x = Whh0[rowA * HIDN + 2*j]; w0A_##j.y = Whh0[rowA * HIDN + 2*j + 1]; \
    w0B_##j.x = Whh0[rowB * HIDN + 2*j]; w0B_##j.y = Whh0[rowB * HIDN + 2*j + 1]; \
    wiA_##j.x = Wih1[rowA * HIDN + 2*j]; wiA_##j.y = Wih1[rowA * HIDN + 2*j + 1]; \
    wiB_##j.x = Wih1[rowB * HIDN + 2*j]; wiB_##j.y = Wih1[rowB * HIDN + 2*j + 1]; \
    whA_##j.x = Whh1[rowA * HIDN + 2*j]; whA_##j.y = Whh1[rowA * HIDN + 2*j + 1]; \
    whB_##j.x = Whh1[rowB * HIDN + 2*j]; whB_##j.y = Whh1[rowB * HIDN + 2*j + 1];
    RJ(LOADW)
#undef LOADW

    float wxAg = Wih0[rowA * 2 + 0], wxAp = Wih0[rowA * 2 + 1];
    float wxBg = Wih0[rowB * 2 + 0], wxBp = Wih0[rowB * 2 + 1];
    float bA0 = bih0[rowA] + bhh0[rowA];
    float bB0 = bih0[rowB] + bhh0[rowB];
    float bA1 = bih1[rowA] + bhh1[rowA];
    float bB1 = bih1[rowB] + bhh1[rowB];
    float wo = valid ? Wout[u] : 0.f;
    const float bo = bout[0];

    // ---- pin per-lane constants into VGPRs (defeat remat/sinking) ----
#define PINW(j) asm volatile("" : "+v"(w0A_##j), "+v"(w0B_##j), "+v"(wiA_##j), \
                                  "+v"(wiB_##j), "+v"(whA_##j), "+v"(whB_##j));
    RJ(PINW)
#undef PINW
    asm volatile("" : "+v"(wxAg), "+v"(wxAp), "+v"(wxBg), "+v"(wxBp));
    asm volatile("" : "+v"(bA0), "+v"(bB0), "+v"(bA1), "+v"(bB1), "+v"(wo));

    const float mA = hB ? 2.0f : 1.0f;
    const float dA = hB ? 1.0f : 0.0f;
    const float cA = -1.4426950408889634f * mA;

    float h0 = 0.f, c0 = 0.f, h1 = 0.f, c1 = 0.f;
    // persistent broadcast pairs (h_2j, h_2j+1), rebuilt after each h update
#define DECLH(j) v2f hp0_##j = {0.f, 0.f}, hp1_##j = {0.f, 0.f};
    RJ(DECLH)
#undef DECLH

    const int t0     = blockIdx.x * CHUNK;
    const int tstart = t0 - WARM;

    float xgv, xpv;
    { int ti = tstart + lane; ti = ti < 0 ? 0 : ti; xgv = grad[ti]; xpv = par[ti]; }

    float rbuf = 0.f;

#pragma unroll 1
    for (int b = 0; b < NB; ++b) {
        float xgn = 0.f, xpn = 0.f;
        if (b + 1 < NB) {
            int ti = tstart + (b + 1) * 64 + lane;
            ti = ti < 0 ? 0 : (ti >= n ? n - 1 : ti);
            xgn = grad[ti]; xpn = par[ti];
        }
        if (b == WARMB && blockIdx.x == 0) {
            // chunk 0: reference's true zero initial state starts exactly here
            h0 = 0.f; c0 = 0.f; h1 = 0.f; c1 = 0.f;
#define ZH(j) hp0_##j.x = 0.f; hp0_##j.y = 0.f; hp1_##j.x = 0.f; hp1_##j.y = 0.f;
            RJ(ZH)
#undef ZH
        }
        const bool main_phase = (b >= WARMB);

#pragma unroll 2
        for (int j = 0; j < 64; ++j) {
            const float xg = bcast(xgv, j);
            const float xp = bcast(xpv, j);

            // ---------------- layer 0 (h0_old pairs hp0_*) ----------------
            v2f aA = {0.f, 0.f}, aB = {0.f, 0.f}, aA2 = {0.f, 0.f}, aB2 = {0.f, 0.f};
#define F0A(j_) aA  = fma2(w0A_##j_, hp0_##j_, aA);  aB  = fma2(w0B_##j_, hp0_##j_, aB);
#define F0B(j_) aA2 = fma2(w0A_##j_, hp0_##j_, aA2); aB2 = fma2(w0B_##j_, hp0_##j_, aB2);
            RJA(F0A) RJB(F0B)
#undef F0A
#undef F0B
            const float xpA = __builtin_fmaf(wxAp, xp, __builtin_fmaf(wxAg, xg, bA0));
            const float xpB = __builtin_fmaf(wxBp, xp, __builtin_fmaf(wxBg, xg, bB0));
            const float a0A = ((aA.x + aA.y) + (aA2.x + aA2.y)) + xpA;
            const float a0B = ((aB.x + aB.y) + (aB2.x + aB2.y)) + xpB;
            h0 = gate_update(a0A, a0B, c0, cA, mA, dA, hB);

            // rebuild h0 pairs (serve layer 1 now and layer 0 next step)
#define RB0(j_) hp0_##j_.x = bperm(h0, 2*j_); hp0_##j_.y = bperm(h0, 2*j_ + 1);
            RJ(RB0)
#undef RB0

            // ---------------- layer 1 (h0_new pairs, h1_old pairs) ----------------
            v2f qA = {0.f, 0.f}, qB = {0.f, 0.f}, qA2 = {0.f, 0.f}, qB2 = {0.f, 0.f};
#define F1A(j_) qA  = fma2(wiA_##j_, hp0_##j_, qA);  qB  = fma2(wiB_##j_, hp0_##j_, qB);
#define F1B(j_) qA2 = fma2(whA_##j_, hp1_##j_, qA2); qB2 = fma2(whB_##j_, hp1_##j_, qB2);
            RJ(F1A) RJ(F1B)
#undef F1A
#undef F1B
            const float a1A = ((qA.x + qA.y) + (qA2.x + qA2.y)) + bA1;
            const float a1B = ((qB.x + qB.y) + (qB2.x + qB2.y)) + bB1;
            h1 = gate_update(a1A, a1B, c1, cA, mA, dA, hB);

            // rebuild h1 pairs (serve layer 1 next step)
#define RB1(j_) hp1_##j_.x = bperm(h1, 2*j_); hp1_##j_.y = bperm(h1, 2*j_ + 1);
            RJ(RB1)
#undef RB1

            // ---------------- output head (f32 shfl tree) ----------------
            if (main_phase) {
                float p = h1 * wo;                 // wo==0 on pad lanes
                p += __shfl_xor(p, 16);
                p += __shfl_xor(p, 8);
                p += __shfl_xor(p, 4);
                p += __shfl_xor(p, 2);
                p += __shfl_xor(p, 1);
                rbuf = (lane == j) ? (p + bo) : rbuf;
            }
        }
        if (main_phase) {
            int t = tstart + b * 64 + lane;
            if (t >= 0 && t < n) out[t] = rbuf;    // coalesced, once per 64 steps
        }
        xgv = xgn; xpv = xpn;
    }
}

extern "C" void kernel_launch(void* const* d_in, const int* in_sizes, int n_in,
                              void* d_out, int out_size, void* d_ws, size_t ws_size,
                              hipStream_t stream) {
    const float* grad = (const float*)d_in[0];
    const float* par  = (const float*)d_in[1];
    const float* Wih0 = (const float*)d_in[2];
    const float* Whh0 = (const float*)d_in[3];
    const float* bih0 = (const float*)d_in[4];
    const float* bhh0 = (const float*)d_in[5];
    const float* Wih1 = (const float*)d_in[6];
    const float* Whh1 = (const float*)d_in[7];
    const float* bih1 = (const float*)d_in[8];
    const float* bhh1 = (const float*)d_in[9];
    const float* Wout = (const float*)d_in[10];
    const float* bout = (const float*)d_in[11];
    float* out = (float*)d_out;

    const int n = in_sizes[0];
    const int chunks = (n + CHUNK - 1) / CHUNK;   // 1024 for n=524288 -> 1 wave/SIMD

    lstm_opt_kernel<<<chunks, 64, 0, stream>>>(grad, par, Wih0, Whh0, bih0, bhh0,
                                               Wih1, Whh1, bih1, bhh1, Wout, bout,
                                               out, n);
}

// Round 11
// 323.325 us; speedup vs baseline: 1.0589x; 1.0589x over previous
//
#include <hip/hip_runtime.h>

#define HIDN 20
#define CHUNK 256
#define WARM 64
#define NB ((CHUNK + WARM) / 64)   // 5 batches of 64 steps
#define WARMB (WARM / 64)          // first batch is warmup

typedef float v2f __attribute__((ext_vector_type(2)));

__device__ __forceinline__ float bcast(float v, int l) {
    return __int_as_float(__builtin_amdgcn_readlane(__float_as_int(v), l));
}
__device__ __forceinline__ float bperm(float v, int srcLane) {
    return __int_as_float(__builtin_amdgcn_ds_bpermute(srcLane << 2, __float_as_int(v)));
}
__device__ __forceinline__ v2f fma2(v2f a, v2f b, v2f c) {
    return __builtin_elementwise_fma(a, b, c);      // -> v_pk_fma_f32 (all-VGPR)
}

// gate-split LSTM cell epilogue (f32). Half A lanes hold gate pre-acts (i,f),
// half B lanes hold (g,o) for the same unit.
__device__ __forceinline__ float gate_update(float aA, float aB, float& c,
                                             float cA, float mA, float dA,
                                             bool hB) {
    const float cB = -1.4426950408889634f;
    const float cT =  2.8853900817779268f;
    float eA = __builtin_amdgcn_exp2f(cA * aA);
    float sA = __builtin_amdgcn_rcpf(1.0f + eA);
    float gA = __builtin_fmaf(mA, sA, -dA);          // i (half A) / g (half B)
    float eB = __builtin_amdgcn_exp2f(cB * aB);
    float gB = __builtin_amdgcn_rcpf(1.0f + eB);     // f (half A) / o (half B)
    float oA = __shfl_xor(gA, 32);
    float oB = __shfl_xor(gB, 32);
    float f = hB ? oB : gB;
    float o = hB ? gB : oB;
    c = __builtin_fmaf(f, c, gA * oA);
    float ec = __builtin_amdgcn_exp2f(cT * c);
    float tc = 1.0f - 2.0f * __builtin_amdgcn_rcpf(ec + 1.0f);
    return o * tc;
}

#define RJ1(M) M(0) M(1) M(2) M(3) M(4) M(5) M(6) M(7) M(8) M(9)
#define RJ2(M,C) M(0,C) M(1,C) M(2,C) M(3,C) M(4,C) M(5,C) M(6,C) M(7,C) M(8,C) M(9,C)

// One 64-lane wave = TWO chunks (2b, 2b+1): two independent recurrence chains
// interleaved in-wave to hide the ~1500-cy per-step dependency latency.
// Weights shared between both chunks (same lane->row mapping). k-axis packed
// v_pk_fma_f32 with ds_bpermute-built h pairs. All f32.
__global__ __launch_bounds__(64)
__attribute__((amdgpu_waves_per_eu(1, 1)))
void lstm_opt_kernel(const float* __restrict__ grad, const float* __restrict__ par,
                     const float* __restrict__ Wih0, const float* __restrict__ Whh0,
                     const float* __restrict__ bih0, const float* __restrict__ bhh0,
                     const float* __restrict__ Wih1, const float* __restrict__ Whh1,
                     const float* __restrict__ bih1, const float* __restrict__ bhh1,
                     const float* __restrict__ Wout, const float* __restrict__ bout,
                     float* __restrict__ out, int n)
{
    const int lane  = threadIdx.x;
    const int lh    = lane & 31;
    const bool hB   = lane >= 32;
    const int u     = (lh < HIDN) ? lh : (HIDN - 1);
    const bool valid = (lh < HIDN);

    const int rowA = (hB ? 2 : 0) * HIDN + u;   // i-row or g-row
    const int rowB = (hB ? 3 : 1) * HIDN + u;   // f-row or o-row

    // ---- k-paired register weights, SHARED by both chunks ----
#define DECLW(j) v2f w0A_##j, w0B_##j, wiA_##j, wiB_##j, whA_##j, whB_##j;
    RJ1(DECLW)
#undef DECLW
#define LOADW(j) \
    w0A_##j.x = Whh0[rowA * HIDN + 2*j]; w0A_##j.y = Whh0[rowA * HIDN + 2*j + 1]; \
    w0B_##j.x = Whh0[rowB * HIDN + 2*j]; w0B_##j.y = Whh0[rowB * HIDN + 2*j + 1]; \
    wiA_##j.x = Wih1[rowA * HIDN + 2*j]; wiA_##j.y = Wih1[rowA * HIDN + 2*j + 1]; \
    wiB_##j.x = Wih1[rowB * HIDN + 2*j]; wiB_##j.y = Wih1[rowB * HIDN + 2*j + 1]; \
    whA_##j.x = Whh1[rowA * HIDN + 2*j]; whA_##j.y = Whh1[rowA * HIDN + 2*j + 1]; \
    whB_##j.x = Whh1[rowB * HIDN + 2*j]; whB_##j.y = Whh1[rowB * HIDN + 2*j + 1];
    RJ1(LOADW)
#undef LOADW

    float wxAg = Wih0[rowA * 2 + 0], wxAp = Wih0[rowA * 2 + 1];
    float wxBg = Wih0[rowB * 2 + 0], wxBp = Wih0[rowB * 2 + 1];
    float bA0 = bih0[rowA] + bhh0[rowA];
    float bB0 = bih0[rowB] + bhh0[rowB];
    float bA1 = bih1[rowA] + bhh1[rowA];
    float bB1 = bih1[rowB] + bhh1[rowB];
    float wo  = valid ? Wout[u] : 0.f;
    const float bo = bout[0];

    // pin the hot weights into VGPRs (defeat remat/sinking); cold consts float free
#define PINW(j) asm volatile("" : "+v"(w0A_##j), "+v"(w0B_##j), "+v"(wiA_##j), \
                                  "+v"(wiB_##j), "+v"(whA_##j), "+v"(whB_##j));
    RJ1(PINW)
#undef PINW

    const float mA = hB ? 2.0f : 1.0f;
    const float dA = hB ? 1.0f : 0.0f;
    const float cA = -1.4426950408889634f * mA;

    // ---- per-chunk state: X = chunk 2b, Y = chunk 2b+1 ----
    float h0X = 0.f, c0X = 0.f, h1X = 0.f, c1X = 0.f;
    float h0Y = 0.f, c0Y = 0.f, h1Y = 0.f, c1Y = 0.f;
#define DECLH(j,c) v2f hp0##c##_##j = {0.f, 0.f}, hp1##c##_##j = {0.f, 0.f};
    RJ2(DECLH,X) RJ2(DECLH,Y)
#undef DECLH

    const int tstartX = (blockIdx.x * 2) * CHUNK - WARM;
    const int tstartY = tstartX + CHUNK;

    float xgvX, xpvX, xgvY, xpvY;
    { int ti = tstartX + lane; ti = ti < 0 ? 0 : ti; xgvX = grad[ti]; xpvX = par[ti]; }
    { int ti = tstartY + lane; xgvY = grad[ti]; xpvY = par[ti]; }

    float rbufX = 0.f, rbufY = 0.f;

#pragma unroll 1
    for (int b = 0; b < NB; ++b) {
        float xgnX = 0.f, xpnX = 0.f, xgnY = 0.f, xpnY = 0.f;
        if (b + 1 < NB) {
            int ti = tstartX + (b + 1) * 64 + lane;
            ti = ti < 0 ? 0 : (ti >= n ? n - 1 : ti);
            xgnX = grad[ti]; xpnX = par[ti];
            int tj = tstartY + (b + 1) * 64 + lane;
            tj = tj < 0 ? 0 : (tj >= n ? n - 1 : tj);
            xgnY = grad[tj]; xpnY = par[tj];
        }
        if (b == WARMB && blockIdx.x == 0) {
            // global chunk 0 (X of block 0): reference's true zero state starts here
            h0X = 0.f; c0X = 0.f; h1X = 0.f; c1X = 0.f;
#define ZH(j) hp0X_##j.x = 0.f; hp0X_##j.y = 0.f; hp1X_##j.x = 0.f; hp1X_##j.y = 0.f;
            RJ1(ZH)
#undef ZH
        }
        const bool main_phase = (b >= WARMB);

#pragma unroll 1
        for (int j = 0; j < 64; ++j) {
            const float xgX = bcast(xgvX, j), xpX = bcast(xpvX, j);
            const float xgY = bcast(xgvY, j), xpY = bcast(xpvY, j);

            // ---------------- layer 0, both chunks ----------------
            v2f aAX = {0.f,0.f}, aBX = {0.f,0.f}, aAY = {0.f,0.f}, aBY = {0.f,0.f};
#define F0(j_,c) aA##c = fma2(w0A_##j_, hp0##c##_##j_, aA##c); \
                 aB##c = fma2(w0B_##j_, hp0##c##_##j_, aB##c);
            RJ2(F0,X) RJ2(F0,Y)
#undef F0
            const float xpAX = __builtin_fmaf(wxAp, xpX, __builtin_fmaf(wxAg, xgX, bA0));
            const float xpBX = __builtin_fmaf(wxBp, xpX, __builtin_fmaf(wxBg, xgX, bB0));
            const float xpAY = __builtin_fmaf(wxAp, xpY, __builtin_fmaf(wxAg, xgY, bA0));
            const float xpBY = __builtin_fmaf(wxBp, xpY, __builtin_fmaf(wxBg, xgY, bB0));
            const float a0AX = (aAX.x + aAX.y) + xpAX;
            const float a0BX = (aBX.x + aBX.y) + xpBX;
            const float a0AY = (aAY.x + aAY.y) + xpAY;
            const float a0BY = (aBY.x + aBY.y) + xpBY;
            h0X = gate_update(a0AX, a0BX, c0X, cA, mA, dA, hB);
            h0Y = gate_update(a0AY, a0BY, c0Y, cA, mA, dA, hB);

            // rebuild h0 pairs (serve layer 1 now and layer 0 next step)
#define RB0(j_,c) hp0##c##_##j_.x = bperm(h0##c, 2*j_); hp0##c##_##j_.y = bperm(h0##c, 2*j_ + 1);
            RJ2(RB0,X) RJ2(RB0,Y)
#undef RB0

            // ---------------- layer 1, both chunks ----------------
            v2f qAX = {0.f,0.f}, qBX = {0.f,0.f}, qAY = {0.f,0.f}, qBY = {0.f,0.f};
#define F1I(j_,c) qA##c = fma2(wiA_##j_, hp0##c##_##j_, qA##c); \
                  qB##c = fma2(wiB_##j_, hp0##c##_##j_, qB##c);
#define F1H(j_,c) qA##c = fma2(whA_##j_, hp1##c##_##j_, qA##c); \
                  qB##c = fma2(whB_##j_, hp1##c##_##j_, qB##c);
            RJ2(F1I,X) RJ2(F1I,Y) RJ2(F1H,X) RJ2(F1H,Y)
#undef F1I
#undef F1H
            const float a1AX = (qAX.x + qAX.y) + bA1;
            const float a1BX = (qBX.x + qBX.y) + bB1;
            const float a1AY = (qAY.x + qAY.y) + bA1;
            const float a1BY = (qBY.x + qBY.y) + bB1;
            h1X = gate_update(a1AX, a1BX, c1X, cA, mA, dA, hB);
            h1Y = gate_update(a1AY, a1BY, c1Y, cA, mA, dA, hB);

            // rebuild h1 pairs
#define RB1(j_,c) hp1##c##_##j_.x = bperm(h1##c, 2*j_); hp1##c##_##j_.y = bperm(h1##c, 2*j_ + 1);
            RJ2(RB1,X) RJ2(RB1,Y)
#undef RB1

            // ---------------- output heads (f32 shfl trees) ----------------
            if (main_phase) {
                float pX = h1X * wo;
                float pY = h1Y * wo;
                pX += __shfl_xor(pX, 16); pY += __shfl_xor(pY, 16);
                pX += __shfl_xor(pX, 8);  pY += __shfl_xor(pY, 8);
                pX += __shfl_xor(pX, 4);  pY += __shfl_xor(pY, 4);
                pX += __shfl_xor(pX, 2);  pY += __shfl_xor(pY, 2);
                pX += __shfl_xor(pX, 1);  pY += __shfl_xor(pY, 1);
                rbufX = (lane == j) ? (pX + bo) : rbufX;
                rbufY = (lane == j) ? (pY + bo) : rbufY;
            }
        }
        if (main_phase) {
            int tX = tstartX + b * 64 + lane;
            if (tX >= 0 && tX < n) out[tX] = rbufX;   // coalesced, once per 64 steps
            int tY = tstartY + b * 64 + lane;
            if (tY >= 0 && tY < n) out[tY] = rbufY;
        }
        xgvX = xgnX; xpvX = xpnX; xgvY = xgnY; xpvY = xpnY;
    }
}

extern "C" void kernel_launch(void* const* d_in, const int* in_sizes, int n_in,
                              void* d_out, int out_size, void* d_ws, size_t ws_size,
                              hipStream_t stream) {
    const float* grad = (const float*)d_in[0];
    const float* par  = (const float*)d_in[1];
    const float* Wih0 = (const float*)d_in[2];
    const float* Whh0 = (const float*)d_in[3];
    const float* bih0 = (const float*)d_in[4];
    const float* bhh0 = (const float*)d_in[5];
    const float* Wih1 = (const float*)d_in[6];
    const float* Whh1 = (const float*)d_in[7];
    const float* bih1 = (const float*)d_in[8];
    const float* bhh1 = (const float*)d_in[9];
    const float* Wout = (const float*)d_in[10];
    const float* bout = (const float*)d_in[11];
    float* out = (float*)d_out;

    const int n = in_sizes[0];
    const int chunks = (n + CHUNK - 1) / CHUNK;   // 2048
    const int blocks = (chunks + 1) / 2;          // 1024 -> 1 wave/SIMD, 2 chains/wave

    lstm_opt_kernel<<<blocks, 64, 0, stream>>>(grad, par, Wih0, Whh0, bih0, bhh0,
                                               Wih1, Whh1, bih1, bhh1, Wout, bout,
                                               out, n);
}

// Round 12
// 236.457 us; speedup vs baseline: 1.4479x; 1.3674x over previous
//
#include <hip/hip_runtime.h>

#define HIDN 20
#define CHUNK 256
#define WARM 64
#define NB ((CHUNK + WARM) / 64)   // 5 batches of 64 steps
#define WARMB (WARM / 64)          // first batch is warmup

typedef float v2f __attribute__((ext_vector_type(2)));

__device__ __forceinline__ float bcast(float v, int l) {
    return __int_as_float(__builtin_amdgcn_readlane(__float_as_int(v), l));
}
__device__ __forceinline__ v2f fma2(v2f a, v2f b, v2f c) {
    return __builtin_elementwise_fma(a, b, c);      // -> v_pk_fma_f32 (all-VGPR)
}

// gate-split LSTM cell epilogue (f32). Half A lanes hold gate pre-acts (i,f),
// half B lanes hold (g,o) for the same unit.
__device__ __forceinline__ float gate_update(float aA, float aB, float& c,
                                             float cA, float mA, float dA,
                                             bool hB) {
    const float cB = -1.4426950408889634f;
    const float cT =  2.8853900817779268f;
    float eA = __builtin_amdgcn_exp2f(cA * aA);
    float sA = __builtin_amdgcn_rcpf(1.0f + eA);
    float gA = __builtin_fmaf(mA, sA, -dA);          // i (half A) / g (half B)
    float eB = __builtin_amdgcn_exp2f(cB * aB);
    float gB = __builtin_amdgcn_rcpf(1.0f + eB);     // f (half A) / o (half B)
    float oA = __shfl_xor(gA, 32);
    float oB = __shfl_xor(gB, 32);
    float f = hB ? oB : gB;
    float o = hB ? gB : oB;
    c = __builtin_fmaf(f, c, gA * oA);
    float ec = __builtin_amdgcn_exp2f(cT * c);
    float tc = 1.0f - 2.0f * __builtin_amdgcn_rcpf(ec + 1.0f);
    return o * tc;
}

#define RJA(M) M(0) M(1) M(2) M(3) M(4)
#define RJB(M) M(5) M(6) M(7) M(8) M(9)
#define RJ(M) RJA(M) RJB(M)

// One 64-lane wave = one chunk of CHUNK steps (WARM discarded warmup steps).
// k-axis-paired v_pk_fma_f32 weights; h broadcast via a 160 B LDS staging
// buffer: every lane writes hbuf[u]=h (dup writes of equal values benign),
// then 5x ds_read_b128 (uniform addr -> broadcast) reload the 10 pairs.
// Replaces 40 ds_bpermute + addr movs with 2 writes + 10 reads per step,
// and drops register demand (~210) under the arch-256 cap.
__global__ __launch_bounds__(64)
__attribute__((amdgpu_waves_per_eu(2, 2)))
void lstm_opt_kernel(const float* __restrict__ grad, const float* __restrict__ par,
                     const float* __restrict__ Wih0, const float* __restrict__ Whh0,
                     const float* __restrict__ bih0, const float* __restrict__ bhh0,
                     const float* __restrict__ Wih1, const float* __restrict__ Whh1,
                     const float* __restrict__ bih1, const float* __restrict__ bhh1,
                     const float* __restrict__ Wout, const float* __restrict__ bout,
                     float* __restrict__ out, int n)
{
    __shared__ __align__(16) float hbuf[40];   // [0..19]=h0, [20..39]=h1

    const int lane  = threadIdx.x;
    const int lh    = lane & 31;
    const bool hB   = lane >= 32;
    const int u     = (lh < HIDN) ? lh : (HIDN - 1);
    const bool valid = (lh < HIDN);

    const int rowA = (hB ? 2 : 0) * HIDN + u;   // i-row or g-row
    const int rowB = (hB ? 3 : 1) * HIDN + u;   // f-row or o-row

    // ---- k-paired register weights (named v2f scalars; no arrays) ----
#define DECLW(j) v2f w0A_##j, w0B_##j, wiA_##j, wiB_##j, whA_##j, whB_##j;
    RJ(DECLW)
#undef DECLW
#define LOADW(j) \
    w0A_##j.x = Whh0[rowA * HIDN + 2*j]; w0A_##j.y = Whh0[rowA * HIDN + 2*j + 1]; \
    w0B_##j.x = Whh0[rowB * HIDN + 2*j]; w0B_##j.y = Whh0[rowB * HIDN + 2*j + 1]; \
    wiA_##j.x = Wih1[rowA * HIDN + 2*j]; wiA_##j.y = Wih1[rowA * HIDN + 2*j + 1]; \
    wiB_##j.x = Wih1[rowB * HIDN + 2*j]; wiB_##j.y = Wih1[rowB * HIDN + 2*j + 1]; \
    whA_##j.x = Whh1[rowA * HIDN + 2*j]; whA_##j.y = Whh1[rowA * HIDN + 2*j + 1]; \
    whB_##j.x = Whh1[rowB * HIDN + 2*j]; whB_##j.y = Whh1[rowB * HIDN + 2*j + 1];
    RJ(LOADW)
#undef LOADW

    float wxAg = Wih0[rowA * 2 + 0], wxAp = Wih0[rowA * 2 + 1];
    float wxBg = Wih0[rowB * 2 + 0], wxBp = Wih0[rowB * 2 + 1];
    float bA0 = bih0[rowA] + bhh0[rowA];
    float bB0 = bih0[rowB] + bhh0[rowB];
    float bA1 = bih1[rowA] + bhh1[rowA];
    float bB1 = bih1[rowB] + bhh1[rowB];
    float wo = valid ? Wout[u] : 0.f;
    const float bo = bout[0];

    // ---- pin per-lane weight constants into VGPRs (defeat remat/sinking) ----
#define PINW(j) asm volatile("" : "+v"(w0A_##j), "+v"(w0B_##j), "+v"(wiA_##j), \
                                  "+v"(wiB_##j), "+v"(whA_##j), "+v"(whB_##j));
    RJ(PINW)
#undef PINW
    asm volatile("" : "+v"(wxAg), "+v"(wxAp), "+v"(wxBg), "+v"(wxBp));
    asm volatile("" : "+v"(bA0), "+v"(bB0), "+v"(bA1), "+v"(bB1), "+v"(wo));

    const float mA = hB ? 2.0f : 1.0f;
    const float dA = hB ? 1.0f : 0.0f;
    const float cA = -1.4426950408889634f * mA;

    float h0 = 0.f, c0 = 0.f, h1 = 0.f, c1 = 0.f;
    // loop-carried broadcast pairs (h_2j, h_2j+1), refreshed from LDS each step
#define DECLH(j) v2f hp0_##j = {0.f, 0.f}, hp1_##j = {0.f, 0.f};
    RJ(DECLH)
#undef DECLH

    const int t0     = blockIdx.x * CHUNK;
    const int tstart = t0 - WARM;

    float xgv, xpv;
    { int ti = tstart + lane; ti = ti < 0 ? 0 : ti; xgv = grad[ti]; xpv = par[ti]; }

    float rbuf = 0.f;

#pragma unroll 1
    for (int b = 0; b < NB; ++b) {
        float xgn = 0.f, xpn = 0.f;
        if (b + 1 < NB) {
            int ti = tstart + (b + 1) * 64 + lane;
            ti = ti < 0 ? 0 : (ti >= n ? n - 1 : ti);
            xgn = grad[ti]; xpn = par[ti];
        }
        if (b == WARMB && blockIdx.x == 0) {
            // chunk 0: reference's true zero initial state starts exactly here
            h0 = 0.f; c0 = 0.f; h1 = 0.f; c1 = 0.f;
#define ZH(j) hp0_##j.x = 0.f; hp0_##j.y = 0.f; hp1_##j.x = 0.f; hp1_##j.y = 0.f;
            RJ(ZH)
#undef ZH
        }
        const bool main_phase = (b >= WARMB);

#pragma unroll 2
        for (int j = 0; j < 64; ++j) {
            const float xg = bcast(xgv, j);
            const float xp = bcast(xpv, j);

            // ---------------- layer 0 (h0_{t-1} pairs hp0_*, in regs) ----------------
            v2f aA = {0.f, 0.f}, aB = {0.f, 0.f}, aA2 = {0.f, 0.f}, aB2 = {0.f, 0.f};
#define F0A(j_) aA  = fma2(w0A_##j_, hp0_##j_, aA);  aB  = fma2(w0B_##j_, hp0_##j_, aB);
#define F0B(j_) aA2 = fma2(w0A_##j_, hp0_##j_, aA2); aB2 = fma2(w0B_##j_, hp0_##j_, aB2);
            RJA(F0A) RJB(F0B)
#undef F0A
#undef F0B
            const float xpA = __builtin_fmaf(wxAp, xp, __builtin_fmaf(wxAg, xg, bA0));
            const float xpB = __builtin_fmaf(wxBp, xp, __builtin_fmaf(wxBg, xg, bB0));
            const float a0A = ((aA.x + aA.y) + (aA2.x + aA2.y)) + xpA;
            const float a0B = ((aB.x + aB.y) + (aB2.x + aB2.y)) + xpB;
            h0 = gate_update(a0A, a0B, c0, cA, mA, dA, hB);

            // publish h0 via LDS, reload as pairs (serves L1 now and L0 next step)
            hbuf[u] = h0;                              // dup same-value writes benign
            {
                const float4 r0 = *reinterpret_cast<const float4*>(&hbuf[0]);
                const float4 r1 = *reinterpret_cast<const float4*>(&hbuf[4]);
                const float4 r2 = *reinterpret_cast<const float4*>(&hbuf[8]);
                const float4 r3 = *reinterpret_cast<const float4*>(&hbuf[12]);
                const float4 r4 = *reinterpret_cast<const float4*>(&hbuf[16]);
                hp0_0.x = r0.x; hp0_0.y = r0.y;  hp0_1.x = r0.z; hp0_1.y = r0.w;
                hp0_2.x = r1.x; hp0_2.y = r1.y;  hp0_3.x = r1.z; hp0_3.y = r1.w;
                hp0_4.x = r2.x; hp0_4.y = r2.y;  hp0_5.x = r2.z; hp0_5.y = r2.w;
                hp0_6.x = r3.x; hp0_6.y = r3.y;  hp0_7.x = r3.z; hp0_7.y = r3.w;
                hp0_8.x = r4.x; hp0_8.y = r4.y;  hp0_9.x = r4.z; hp0_9.y = r4.w;
            }

            // ---------------- layer 1 (h0_t pairs, h1_{t-1} pairs) ----------------
            v2f qA = {0.f, 0.f}, qB = {0.f, 0.f}, qA2 = {0.f, 0.f}, qB2 = {0.f, 0.f};
#define F1A(j_) qA  = fma2(wiA_##j_, hp0_##j_, qA);  qB  = fma2(wiB_##j_, hp0_##j_, qB);
#define F1B(j_) qA2 = fma2(whA_##j_, hp1_##j_, qA2); qB2 = fma2(whB_##j_, hp1_##j_, qB2);
            RJ(F1A) RJ(F1B)
#undef F1A
#undef F1B
            const float a1A = ((qA.x + qA.y) + (qA2.x + qA2.y)) + bA1;
            const float a1B = ((qB.x + qB.y) + (qB2.x + qB2.y)) + bB1;
            h1 = gate_update(a1A, a1B, c1, cA, mA, dA, hB);

            // publish h1 via LDS, reload pairs (serve L1 next step)
            hbuf[HIDN + u] = h1;
            {
                const float4 r0 = *reinterpret_cast<const float4*>(&hbuf[20]);
                const float4 r1 = *reinterpret_cast<const float4*>(&hbuf[24]);
                const float4 r2 = *reinterpret_cast<const float4*>(&hbuf[28]);
                const float4 r3 = *reinterpret_cast<const float4*>(&hbuf[32]);
                const float4 r4 = *reinterpret_cast<const float4*>(&hbuf[36]);
                hp1_0.x = r0.x; hp1_0.y = r0.y;  hp1_1.x = r0.z; hp1_1.y = r0.w;
                hp1_2.x = r1.x; hp1_2.y = r1.y;  hp1_3.x = r1.z; hp1_3.y = r1.w;
                hp1_4.x = r2.x; hp1_4.y = r2.y;  hp1_5.x = r2.z; hp1_5.y = r2.w;
                hp1_6.x = r3.x; hp1_6.y = r3.y;  hp1_7.x = r3.z; hp1_7.y = r3.w;
                hp1_8.x = r4.x; hp1_8.y = r4.y;  hp1_9.x = r4.z; hp1_9.y = r4.w;
            }

            // ---------------- output head (f32 shfl tree) ----------------
            if (main_phase) {
                float p = h1 * wo;                 // wo==0 on pad lanes
                p += __shfl_xor(p, 16);
                p += __shfl_xor(p, 8);
                p += __shfl_xor(p, 4);
                p += __shfl_xor(p, 2);
                p += __shfl_xor(p, 1);
                rbuf = (lane == j) ? (p + bo) : rbuf;
            }
        }
        if (main_phase) {
            int t = tstart + b * 64 + lane;
            if (t >= 0 && t < n) out[t] = rbuf;    // coalesced, once per 64 steps
        }
        xgv = xgn; xpv = xpn;
    }
}

extern "C" void kernel_launch(void* const* d_in, const int* in_sizes, int n_in,
                              void* d_out, int out_size, void* d_ws, size_t ws_size,
                              hipStream_t stream) {
    const float* grad = (const float*)d_in[0];
    const float* par  = (const float*)d_in[1];
    const float* Wih0 = (const float*)d_in[2];
    const float* Whh0 = (const float*)d_in[3];
    const float* bih0 = (const float*)d_in[4];
    const float* bhh0 = (const float*)d_in[5];
    const float* Wih1 = (const float*)d_in[6];
    const float* Whh1 = (const float*)d_in[7];
    const float* bih1 = (const float*)d_in[8];
    const float* bhh1 = (const float*)d_in[9];
    const float* Wout = (const float*)d_in[10];
    const float* bout = (const float*)d_in[11];
    float* out = (float*)d_out;

    const int n = in_sizes[0];
    const int chunks = (n + CHUNK - 1) / CHUNK;   // 2048 for n=524288 -> 2 waves/SIMD

    lstm_opt_kernel<<<chunks, 64, 0, stream>>>(grad, par, Wih0, Whh0, bih0, bhh0,
                                               Wih1, Whh1, bih1, bhh1, Wout, bout,
                                               out, n);
}

// Round 13
// 229.794 us; speedup vs baseline: 1.4899x; 1.0290x over previous
//
#include <hip/hip_runtime.h>

#define HIDN 20
#define CHUNK 256
#define WARM 64
#define NB ((CHUNK + WARM) / 64)   // 5 batches of 64 steps
#define WARMB (WARM / 64)          // first batch is warmup

typedef float v2f __attribute__((ext_vector_type(2)));

__device__ __forceinline__ float bcast(float v, int l) {
    return __int_as_float(__builtin_amdgcn_readlane(__float_as_int(v), l));
}
__device__ __forceinline__ v2f fma2(v2f a, v2f b, v2f c) {
    return __builtin_elementwise_fma(a, b, c);      // -> v_pk_fma_f32 (all-VGPR)
}

// gate-split LSTM cell epilogue (f32). Half A lanes hold gate pre-acts (i,f),
// half B lanes hold (g,o) for the same unit.
__device__ __forceinline__ float gate_update(float aA, float aB, float& c,
                                             float cA, float mA, float dA,
                                             bool hB) {
    const float cB = -1.4426950408889634f;
    const float cT =  2.8853900817779268f;
    float eA = __builtin_amdgcn_exp2f(cA * aA);
    float sA = __builtin_amdgcn_rcpf(1.0f + eA);
    float gA = __builtin_fmaf(mA, sA, -dA);          // i (half A) / g (half B)
    float eB = __builtin_amdgcn_exp2f(cB * aB);
    float gB = __builtin_amdgcn_rcpf(1.0f + eB);     // f (half A) / o (half B)
    float oA = __shfl_xor(gA, 32);
    float oB = __shfl_xor(gB, 32);
    float f = hB ? oB : gB;
    float o = hB ? gB : oB;
    c = __builtin_fmaf(f, c, gA * oA);
    float ec = __builtin_amdgcn_exp2f(cT * c);
    float tc = 1.0f - 2.0f * __builtin_amdgcn_rcpf(ec + 1.0f);
    return o * tc;
}

#define RJA(M) M(0) M(1) M(2) M(3) M(4)
#define RJB(M) M(5) M(6) M(7) M(8) M(9)
#define RJ(M) RJA(M) RJB(M)

// One 64-lane wave = one chunk. SOFTWARE-PIPELINED layers: each iteration
// enters with h0(t), h1(t-1) already published in LDS; it reloads the pairs
// once, then computes L1(t) and L0(t+1) -- mutually independent -- then two
// independent gate chains, then publishes h0(t+1), h1(t) for the next step.
// Halves the per-step carried dependency chain vs the sequential L0->L1 form.
__global__ __launch_bounds__(64)
__attribute__((amdgpu_waves_per_eu(2, 2)))
void lstm_opt_kernel(const float* __restrict__ grad, const float* __restrict__ par,
                     const float* __restrict__ Wih0, const float* __restrict__ Whh0,
                     const float* __restrict__ bih0, const float* __restrict__ bhh0,
                     const float* __restrict__ Wih1, const float* __restrict__ Whh1,
                     const float* __restrict__ bih1, const float* __restrict__ bhh1,
                     const float* __restrict__ Wout, const float* __restrict__ bout,
                     float* __restrict__ out, int n)
{
    __shared__ __align__(16) float hbuf[40];   // [0..19]=h0(t), [20..39]=h1(t-1)

    const int lane  = threadIdx.x;
    const int lh    = lane & 31;
    const bool hB   = lane >= 32;
    const int u     = (lh < HIDN) ? lh : (HIDN - 1);
    const bool valid = (lh < HIDN);

    const int rowA = (hB ? 2 : 0) * HIDN + u;   // i-row or g-row
    const int rowB = (hB ? 3 : 1) * HIDN + u;   // f-row or o-row

    // ---- k-paired register weights (named v2f scalars; no arrays) ----
#define DECLW(j) v2f w0A_##j, w0B_##j, wiA_##j, wiB_##j, whA_##j, whB_##j;
    RJ(DECLW)
#undef DECLW
#define LOADW(j) \
    w0A_##j.x = Whh0[rowA * HIDN + 2*j]; w0A_##j.y = Whh0[rowA * HIDN + 2*j + 1]; \
    w0B_##j.x = Whh0[rowB * HIDN + 2*j]; w0B_##j.y = Whh0[rowB * HIDN + 2*j + 1]; \
    wiA_##j.x = Wih1[rowA * HIDN + 2*j]; wiA_##j.y = Wih1[rowA * HIDN + 2*j + 1]; \
    wiB_##j.x = Wih1[rowB * HIDN + 2*j]; wiB_##j.y = Wih1[rowB * HIDN + 2*j + 1]; \
    whA_##j.x = Whh1[rowA * HIDN + 2*j]; whA_##j.y = Whh1[rowA * HIDN + 2*j + 1]; \
    whB_##j.x = Whh1[rowB * HIDN + 2*j]; whB_##j.y = Whh1[rowB * HIDN + 2*j + 1];
    RJ(LOADW)
#undef LOADW

    float wxAg = Wih0[rowA * 2 + 0], wxAp = Wih0[rowA * 2 + 1];
    float wxBg = Wih0[rowB * 2 + 0], wxBp = Wih0[rowB * 2 + 1];
    float bA0 = bih0[rowA] + bhh0[rowA];
    float bB0 = bih0[rowB] + bhh0[rowB];
    float bA1 = bih1[rowA] + bhh1[rowA];
    float bB1 = bih1[rowB] + bhh1[rowB];
    float wo = valid ? Wout[u] : 0.f;
    const float bo = bout[0];

    // ---- pin per-lane weight constants into VGPRs (defeat remat/sinking) ----
#define PINW(j) asm volatile("" : "+v"(w0A_##j), "+v"(w0B_##j), "+v"(wiA_##j), \
                                  "+v"(wiB_##j), "+v"(whA_##j), "+v"(whB_##j));
    RJ(PINW)
#undef PINW
    asm volatile("" : "+v"(wxAg), "+v"(wxAp), "+v"(wxBg), "+v"(wxBp));
    asm volatile("" : "+v"(bA0), "+v"(bB0), "+v"(bA1), "+v"(bB1), "+v"(wo));

    const float mA = hB ? 2.0f : 1.0f;
    const float dA = hB ? 1.0f : 0.0f;
    const float cA = -1.4426950408889634f * mA;

    float c0 = 0.f, c1 = 0.f;

    const int t0     = blockIdx.x * CHUNK;
    const int tstart = t0 - WARM;

    float xgv, xpv;
    { int ti = tstart + lane; ti = ti < 0 ? 0 : ti; xgv = grad[ti]; xpv = par[ti]; }

    // ---- prologue: h0(tstart) from zero state; h1(tstart-1)=0. Publish. ----
    {
        const float xg0 = bcast(xgv, 0), xp0 = bcast(xpv, 0);
        const float pA = __builtin_fmaf(wxAp, xp0, __builtin_fmaf(wxAg, xg0, bA0));
        const float pB = __builtin_fmaf(wxBp, xp0, __builtin_fmaf(wxBg, xg0, bB0));
        c0 = 0.f;
        const float h0i = gate_update(pA, pB, c0, cA, mA, dA, hB);
        hbuf[u] = h0i;
        hbuf[HIDN + u] = 0.f;
        c1 = 0.f;
    }

    float rbuf = 0.f;

#pragma unroll 1
    for (int b = 0; b < NB; ++b) {
        float xgn = 0.f, xpn = 0.f;
        if (b + 1 < NB) {
            int ti = tstart + (b + 1) * 64 + lane;
            ti = ti < 0 ? 0 : (ti >= n ? n - 1 : ti);
            xgn = grad[ti]; xpn = par[ti];
        }
        if (b == WARMB && blockIdx.x == 0) {
            // chunk 0: exact zero-state restart at t=0. Recompute h0(0) from
            // x(0) (lane 0 of this batch), republish h0(0), h1(-1)=0.
            const float xg0 = bcast(xgv, 0), xp0 = bcast(xpv, 0);
            const float pA = __builtin_fmaf(wxAp, xp0, __builtin_fmaf(wxAg, xg0, bA0));
            const float pB = __builtin_fmaf(wxBp, xp0, __builtin_fmaf(wxBg, xg0, bB0));
            c0 = 0.f;
            const float h0i = gate_update(pA, pB, c0, cA, mA, dA, hB);
            hbuf[u] = h0i;
            hbuf[HIDN + u] = 0.f;
            c1 = 0.f;
        }
        const bool main_phase = (b >= WARMB);

#pragma unroll 2
        for (int j = 0; j < 64; ++j) {
            // x(t+1): from this batch, or lane 0 of the next at the seam
            const int ln = (j + 1) & 63;
            const float xgN = bcast((j < 63) ? xgv : xgn, ln);
            const float xpN = bcast((j < 63) ? xpv : xpn, ln);

            // ---- reload pairs published at end of previous iteration ----
            v2f hp0_0, hp0_1, hp0_2, hp0_3, hp0_4, hp0_5, hp0_6, hp0_7, hp0_8, hp0_9;
            v2f hp1_0, hp1_1, hp1_2, hp1_3, hp1_4, hp1_5, hp1_6, hp1_7, hp1_8, hp1_9;
            {
                const float4 r0 = *reinterpret_cast<const float4*>(&hbuf[0]);
                const float4 r1 = *reinterpret_cast<const float4*>(&hbuf[4]);
                const float4 r2 = *reinterpret_cast<const float4*>(&hbuf[8]);
                const float4 r3 = *reinterpret_cast<const float4*>(&hbuf[12]);
                const float4 r4 = *reinterpret_cast<const float4*>(&hbuf[16]);
                hp0_0.x = r0.x; hp0_0.y = r0.y;  hp0_1.x = r0.z; hp0_1.y = r0.w;
                hp0_2.x = r1.x; hp0_2.y = r1.y;  hp0_3.x = r1.z; hp0_3.y = r1.w;
                hp0_4.x = r2.x; hp0_4.y = r2.y;  hp0_5.x = r2.z; hp0_5.y = r2.w;
                hp0_6.x = r3.x; hp0_6.y = r3.y;  hp0_7.x = r3.z; hp0_7.y = r3.w;
                hp0_8.x = r4.x; hp0_8.y = r4.y;  hp0_9.x = r4.z; hp0_9.y = r4.w;
                const float4 s0 = *reinterpret_cast<const float4*>(&hbuf[20]);
                const float4 s1 = *reinterpret_cast<const float4*>(&hbuf[24]);
                const float4 s2 = *reinterpret_cast<const float4*>(&hbuf[28]);
                const float4 s3 = *reinterpret_cast<const float4*>(&hbuf[32]);
                const float4 s4 = *reinterpret_cast<const float4*>(&hbuf[36]);
                hp1_0.x = s0.x; hp1_0.y = s0.y;  hp1_1.x = s0.z; hp1_1.y = s0.w;
                hp1_2.x = s1.x; hp1_2.y = s1.y;  hp1_3.x = s1.z; hp1_3.y = s1.w;
                hp1_4.x = s2.x; hp1_4.y = s2.y;  hp1_5.x = s2.z; hp1_5.y = s2.w;
                hp1_6.x = s3.x; hp1_6.y = s3.y;  hp1_7.x = s3.z; hp1_7.y = s3.w;
                hp1_8.x = s4.x; hp1_8.y = s4.y;  hp1_9.x = s4.z; hp1_9.y = s4.w;
            }

            // ---- L1(t) matvec: h1 preact from hp0 (=h0(t)) and hp1 (=h1(t-1)) ----
            v2f qA = {0.f, 0.f}, qB = {0.f, 0.f}, qA2 = {0.f, 0.f}, qB2 = {0.f, 0.f};
#define F1A(j_) qA  = fma2(wiA_##j_, hp0_##j_, qA);  qB  = fma2(wiB_##j_, hp0_##j_, qB);
#define F1B(j_) qA2 = fma2(whA_##j_, hp1_##j_, qA2); qB2 = fma2(whB_##j_, hp1_##j_, qB2);
            RJ(F1A) RJ(F1B)
#undef F1A
#undef F1B

            // ---- L0(t+1) matvec: h0 preact from hp0 and x(t+1) (independent) ----
            v2f aA = {0.f, 0.f}, aB = {0.f, 0.f}, aA2 = {0.f, 0.f}, aB2 = {0.f, 0.f};
#define F0A(j_) aA  = fma2(w0A_##j_, hp0_##j_, aA);  aB  = fma2(w0B_##j_, hp0_##j_, aB);
#define F0B(j_) aA2 = fma2(w0A_##j_, hp0_##j_, aA2); aB2 = fma2(w0B_##j_, hp0_##j_, aB2);
            RJA(F0A) RJB(F0B)
#undef F0A
#undef F0B

            const float a1A = ((qA.x + qA.y) + (qA2.x + qA2.y)) + bA1;
            const float a1B = ((qB.x + qB.y) + (qB2.x + qB2.y)) + bB1;
            const float xpA = __builtin_fmaf(wxAp, xpN, __builtin_fmaf(wxAg, xgN, bA0));
            const float xpB = __builtin_fmaf(wxBp, xpN, __builtin_fmaf(wxBg, xgN, bB0));
            const float a0A = ((aA.x + aA.y) + (aA2.x + aA2.y)) + xpA;
            const float a0B = ((aB.x + aB.y) + (aB2.x + aB2.y)) + xpB;

            // ---- two independent gate chains ----
            const float h1cur  = gate_update(a1A, a1B, c1, cA, mA, dA, hB);  // h1(t)
            const float h0next = gate_update(a0A, a0B, c0, cA, mA, dA, hB);  // h0(t+1)

            // ---- publish for next iteration ----
            hbuf[u] = h0next;
            hbuf[HIDN + u] = h1cur;

            // ---- output head on h1(t) (f32 shfl tree) ----
            if (main_phase) {
                float p = h1cur * wo;              // wo==0 on pad lanes
                p += __shfl_xor(p, 16);
                p += __shfl_xor(p, 8);
                p += __shfl_xor(p, 4);
                p += __shfl_xor(p, 2);
                p += __shfl_xor(p, 1);
                rbuf = (lane == j) ? (p + bo) : rbuf;
            }
        }
        if (main_phase) {
            int t = tstart + b * 64 + lane;
            if (t >= 0 && t < n) out[t] = rbuf;    // coalesced, once per 64 steps
        }
        xgv = xgn; xpv = xpn;
    }
}

extern "C" void kernel_launch(void* const* d_in, const int* in_sizes, int n_in,
                              void* d_out, int out_size, void* d_ws, size_t ws_size,
                              hipStream_t stream) {
    const float* grad = (const float*)d_in[0];
    const float* par  = (const float*)d_in[1];
    const float* Wih0 = (const float*)d_in[2];
    const float* Whh0 = (const float*)d_in[3];
    const float* bih0 = (const float*)d_in[4];
    const float* bhh0 = (const float*)d_in[5];
    const float* Wih1 = (const float*)d_in[6];
    const float* Whh1 = (const float*)d_in[7];
    const float* bih1 = (const float*)d_in[8];
    const float* bhh1 = (const float*)d_in[9];
    const float* Wout = (const float*)d_in[10];
    const float* bout = (const float*)d_in[11];
    float* out = (float*)d_out;

    const int n = in_sizes[0];
    const int chunks = (n + CHUNK - 1) / CHUNK;   // 2048 for n=524288 -> 2 waves/SIMD

    lstm_opt_kernel<<<chunks, 64, 0, stream>>>(grad, par, Wih0, Whh0, bih0, bhh0,
                                               Wih1, Whh1, bih1, bhh1, Wout, bout,
                                               out, n);
}

// Round 15
// 211.519 us; speedup vs baseline: 1.6187x; 1.0864x over previous
//
#include <hip/hip_runtime.h>

#define HIDN 20
#define CHUNK 256
#define WARM 64
#define NB ((CHUNK + WARM) / 64)   // 5 batches of 64 steps
#define WARMB (WARM / 64)          // first batch is warmup

typedef float v2f __attribute__((ext_vector_type(2)));
typedef unsigned int v2u __attribute__((ext_vector_type(2)));

__device__ __forceinline__ float bcast(float v, int l) {
    return __int_as_float(__builtin_amdgcn_readlane(__float_as_int(v), l));
}
__device__ __forceinline__ v2f fma2(v2f a, v2f b, v2f c) {
    return __builtin_elementwise_fma(a, b, c);      // -> v_pk_fma_f32 (all-VGPR)
}
// lane[i] <-> lane[i^32] exchange. Builtin permlane32_swap returns BOTH
// results; with equal inputs the per-lane pair {r.x,r.y} = {g, g[lane^32]}
// under either swap direction, so r.x^r.y^g is the exchanged value --
// bit-exact, direction-agnostic, VALU-pipe (no DS round trip).
__device__ __forceinline__ float xchg32(float g) {
#if __has_builtin(__builtin_amdgcn_permlane32_swap)
    const unsigned int gu = __float_as_uint(g);
    const v2u r = __builtin_amdgcn_permlane32_swap(gu, gu, false, false);
    return __uint_as_float(r.x ^ r.y ^ gu);
#else
    return __shfl_xor(g, 32);
#endif
}

// gate-split LSTM cell epilogue (f32). Half A lanes hold gate pre-acts (i,f),
// half B lanes hold (g,o) for the same unit.
__device__ __forceinline__ float gate_update(float aA, float aB, float& c,
                                             float cA, float mA, float dA,
                                             bool hB) {
    const float cB = -1.4426950408889634f;
    const float cT =  2.8853900817779268f;
    float eA = __builtin_amdgcn_exp2f(cA * aA);
    float sA = __builtin_amdgcn_rcpf(1.0f + eA);
    float gA = __builtin_fmaf(mA, sA, -dA);          // i (half A) / g (half B)
    float eB = __builtin_amdgcn_exp2f(cB * aB);
    float gB = __builtin_amdgcn_rcpf(1.0f + eB);     // f (half A) / o (half B)
    float oA = xchg32(gA);
    float oB = xchg32(gB);
    float f = hB ? oB : gB;
    float o = hB ? gB : oB;
    c = __builtin_fmaf(f, c, gA * oA);
    float ec = __builtin_amdgcn_exp2f(cT * c);
    float tc = 1.0f - 2.0f * __builtin_amdgcn_rcpf(ec + 1.0f);
    return o * tc;
}

#define RJA(M) M(0) M(1) M(2) M(3) M(4)
#define RJB(M) M(5) M(6) M(7) M(8) M(9)
#define RJ(M) RJA(M) RJB(M)

// One 64-lane wave = one chunk. Software-pipelined layers (L1(t) ∥ L0(t+1)).
// h broadcast via 160 B LDS buffer; per-step output contributions parked in
// hstore[step][unit] and reduced once per 64-step batch (deferred head).
__global__ __launch_bounds__(64)
__attribute__((amdgpu_waves_per_eu(2, 2)))
void lstm_opt_kernel(const float* __restrict__ grad, const float* __restrict__ par,
                     const float* __restrict__ Wih0, const float* __restrict__ Whh0,
                     const float* __restrict__ bih0, const float* __restrict__ bhh0,
                     const float* __restrict__ Wih1, const float* __restrict__ Whh1,
                     const float* __restrict__ bih1, const float* __restrict__ bhh1,
                     const float* __restrict__ Wout, const float* __restrict__ bout,
                     float* __restrict__ out, int n)
{
    __shared__ __align__(16) float hbuf[40];        // [0..19]=h0(t), [20..39]=h1(t-1)
    __shared__ __align__(16) float hstore[64][24];  // per-step h1*wo, stride 24

    const int lane  = threadIdx.x;
    const int lh    = lane & 31;
    const bool hB   = lane >= 32;
    const int u     = (lh < HIDN) ? lh : (HIDN - 1);
    const bool valid = (lh < HIDN);
    // invalid lanes park their (zero) head writes in pad columns 20..23
    const int wcol  = valid ? lh : (HIDN + (lane & 3));

    const int rowA = (hB ? 2 : 0) * HIDN + u;   // i-row or g-row
    const int rowB = (hB ? 3 : 1) * HIDN + u;   // f-row or o-row

    // ---- k-paired register weights (named v2f scalars; no arrays) ----
#define DECLW(j) v2f w0A_##j, w0B_##j, wiA_##j, wiB_##j, whA_##j, whB_##j;
    RJ(DECLW)
#undef DECLW
#define LOADW(j) \
    w0A_##j.x = Whh0[rowA * HIDN + 2*j]; w0A_##j.y = Whh0[rowA * HIDN + 2*j + 1]; \
    w0B_##j.x = Whh0[rowB * HIDN + 2*j]; w0B_##j.y = Whh0[rowB * HIDN + 2*j + 1]; \
    wiA_##j.x = Wih1[rowA * HIDN + 2*j]; wiA_##j.y = Wih1[rowA * HIDN + 2*j + 1]; \
    wiB_##j.x = Wih1[rowB * HIDN + 2*j]; wiB_##j.y = Wih1[rowB * HIDN + 2*j + 1]; \
    whA_##j.x = Whh1[rowA * HIDN + 2*j]; whA_##j.y = Whh1[rowA * HIDN + 2*j + 1]; \
    whB_##j.x = Whh1[rowB * HIDN + 2*j]; whB_##j.y = Whh1[rowB * HIDN + 2*j + 1];
    RJ(LOADW)
#undef LOADW

    float wxAg = Wih0[rowA * 2 + 0], wxAp = Wih0[rowA * 2 + 1];
    float wxBg = Wih0[rowB * 2 + 0], wxBp = Wih0[rowB * 2 + 1];
    float bA0 = bih0[rowA] + bhh0[rowA];
    float bB0 = bih0[rowB] + bhh0[rowB];
    float bA1 = bih1[rowA] + bhh1[rowA];
    float bB1 = bih1[rowB] + bhh1[rowB];
    float wo = valid ? Wout[u] : 0.f;
    const float bo = bout[0];

    // ---- pin per-lane weight constants into VGPRs (defeat remat/sinking) ----
#define PINW(j) asm volatile("" : "+v"(w0A_##j), "+v"(w0B_##j), "+v"(wiA_##j), \
                                  "+v"(wiB_##j), "+v"(whA_##j), "+v"(whB_##j));
    RJ(PINW)
#undef PINW
    asm volatile("" : "+v"(wxAg), "+v"(wxAp), "+v"(wxBg), "+v"(wxBp));
    asm volatile("" : "+v"(bA0), "+v"(bB0), "+v"(bA1), "+v"(bB1), "+v"(wo));

    const float mA = hB ? 2.0f : 1.0f;
    const float dA = hB ? 1.0f : 0.0f;
    const float cA = -1.4426950408889634f * mA;

    float c0 = 0.f, c1 = 0.f;

    const int t0     = blockIdx.x * CHUNK;
    const int tstart = t0 - WARM;

    float xgv, xpv;
    { int ti = tstart + lane; ti = ti < 0 ? 0 : ti; xgv = grad[ti]; xpv = par[ti]; }

    // ---- prologue: h0(tstart) from zero state; h1(tstart-1)=0. Publish. ----
    {
        const float xg0 = bcast(xgv, 0), xp0 = bcast(xpv, 0);
        const float pA = __builtin_fmaf(wxAp, xp0, __builtin_fmaf(wxAg, xg0, bA0));
        const float pB = __builtin_fmaf(wxBp, xp0, __builtin_fmaf(wxBg, xg0, bB0));
        c0 = 0.f;
        const float h0i = gate_update(pA, pB, c0, cA, mA, dA, hB);
        hbuf[u] = h0i;
        hbuf[HIDN + u] = 0.f;
        c1 = 0.f;
    }

#pragma unroll 1
    for (int b = 0; b < NB; ++b) {
        float xgn = 0.f, xpn = 0.f;
        if (b + 1 < NB) {
            int ti = tstart + (b + 1) * 64 + lane;
            ti = ti < 0 ? 0 : (ti >= n ? n - 1 : ti);
            xgn = grad[ti]; xpn = par[ti];
        }
        if (b == WARMB && blockIdx.x == 0) {
            // chunk 0: exact zero-state restart at t=0. Recompute h0(0) from
            // x(0) (lane 0 of this batch), republish h0(0), h1(-1)=0.
            const float xg0 = bcast(xgv, 0), xp0 = bcast(xpv, 0);
            const float pA = __builtin_fmaf(wxAp, xp0, __builtin_fmaf(wxAg, xg0, bA0));
            const float pB = __builtin_fmaf(wxBp, xp0, __builtin_fmaf(wxBg, xg0, bB0));
            c0 = 0.f;
            const float h0i = gate_update(pA, pB, c0, cA, mA, dA, hB);
            hbuf[u] = h0i;
            hbuf[HIDN + u] = 0.f;
            c1 = 0.f;
        }
        const bool main_phase = (b >= WARMB);

#pragma unroll 2
        for (int j = 0; j < 64; ++j) {
            // x(t+1): from this batch, or lane 0 of the next at the seam
            const int ln = (j + 1) & 63;
            const float xgN = bcast((j < 63) ? xgv : xgn, ln);
            const float xpN = bcast((j < 63) ? xpv : xpn, ln);

            // ---- reload pairs published at end of previous iteration ----
            v2f hp0_0, hp0_1, hp0_2, hp0_3, hp0_4, hp0_5, hp0_6, hp0_7, hp0_8, hp0_9;
            v2f hp1_0, hp1_1, hp1_2, hp1_3, hp1_4, hp1_5, hp1_6, hp1_7, hp1_8, hp1_9;
            {
                const float4 r0 = *reinterpret_cast<const float4*>(&hbuf[0]);
                const float4 r1 = *reinterpret_cast<const float4*>(&hbuf[4]);
                const float4 r2 = *reinterpret_cast<const float4*>(&hbuf[8]);
                const float4 r3 = *reinterpret_cast<const float4*>(&hbuf[12]);
                const float4 r4 = *reinterpret_cast<const float4*>(&hbuf[16]);
                hp0_0.x = r0.x; hp0_0.y = r0.y;  hp0_1.x = r0.z; hp0_1.y = r0.w;
                hp0_2.x = r1.x; hp0_2.y = r1.y;  hp0_3.x = r1.z; hp0_3.y = r1.w;
                hp0_4.x = r2.x; hp0_4.y = r2.y;  hp0_5.x = r2.z; hp0_5.y = r2.w;
                hp0_6.x = r3.x; hp0_6.y = r3.y;  hp0_7.x = r3.z; hp0_7.y = r3.w;
                hp0_8.x = r4.x; hp0_8.y = r4.y;  hp0_9.x = r4.z; hp0_9.y = r4.w;
                const float4 s0 = *reinterpret_cast<const float4*>(&hbuf[20]);
                const float4 s1 = *reinterpret_cast<const float4*>(&hbuf[24]);
                const float4 s2 = *reinterpret_cast<const float4*>(&hbuf[28]);
                const float4 s3 = *reinterpret_cast<const float4*>(&hbuf[32]);
                const float4 s4 = *reinterpret_cast<const float4*>(&hbuf[36]);
                hp1_0.x = s0.x; hp1_0.y = s0.y;  hp1_1.x = s0.z; hp1_1.y = s0.w;
                hp1_2.x = s1.x; hp1_2.y = s1.y;  hp1_3.x = s1.z; hp1_3.y = s1.w;
                hp1_4.x = s2.x; hp1_4.y = s2.y;  hp1_5.x = s2.z; hp1_5.y = s2.w;
                hp1_6.x = s3.x; hp1_6.y = s3.y;  hp1_7.x = s3.z; hp1_7.y = s3.w;
                hp1_8.x = s4.x; hp1_8.y = s4.y;  hp1_9.x = s4.z; hp1_9.y = s4.w;
            }

            // ---- L1(t) matvec: h1 preact from hp0 (=h0(t)) and hp1 (=h1(t-1)) ----
            v2f qA = {0.f, 0.f}, qB = {0.f, 0.f}, qA2 = {0.f, 0.f}, qB2 = {0.f, 0.f};
#define F1A(j_) qA  = fma2(wiA_##j_, hp0_##j_, qA);  qB  = fma2(wiB_##j_, hp0_##j_, qB);
#define F1B(j_) qA2 = fma2(whA_##j_, hp1_##j_, qA2); qB2 = fma2(whB_##j_, hp1_##j_, qB2);
            RJ(F1A) RJ(F1B)
#undef F1A
#undef F1B

            // ---- L0(t+1) matvec: h0 preact from hp0 and x(t+1) (independent) ----
            v2f aA = {0.f, 0.f}, aB = {0.f, 0.f}, aA2 = {0.f, 0.f}, aB2 = {0.f, 0.f};
#define F0A(j_) aA  = fma2(w0A_##j_, hp0_##j_, aA);  aB  = fma2(w0B_##j_, hp0_##j_, aB);
#define F0B(j_) aA2 = fma2(w0A_##j_, hp0_##j_, aA2); aB2 = fma2(w0B_##j_, hp0_##j_, aB2);
            RJA(F0A) RJB(F0B)
#undef F0A
#undef F0B

            const float a1A = ((qA.x + qA.y) + (qA2.x + qA2.y)) + bA1;
            const float a1B = ((qB.x + qB.y) + (qB2.x + qB2.y)) + bB1;
            const float xpA = __builtin_fmaf(wxAp, xpN, __builtin_fmaf(wxAg, xgN, bA0));
            const float xpB = __builtin_fmaf(wxBp, xpN, __builtin_fmaf(wxBg, xgN, bB0));
            const float a0A = ((aA.x + aA.y) + (aA2.x + aA2.y)) + xpA;
            const float a0B = ((aB.x + aB.y) + (aB2.x + aB2.y)) + xpB;

            // ---- two independent gate chains ----
            const float h1cur  = gate_update(a1A, a1B, c1, cA, mA, dA, hB);  // h1(t)
            const float h0next = gate_update(a0A, a0B, c0, cA, mA, dA, hB);  // h0(t+1)

            // ---- publish for next iteration ----
            hbuf[u] = h0next;
            hbuf[HIDN + u] = h1cur;

            // ---- deferred head: park h1(t)*wo, reduce at batch end ----
            hstore[j][wcol] = h1cur * wo;          // dup/pad writes benign (bit-identical)
        }

        if (main_phase) {
            // each lane reduces ONE step's 20 contributions (5x ds_read_b128)
            const float4 a0 = *reinterpret_cast<const float4*>(&hstore[lane][0]);
            const float4 a1 = *reinterpret_cast<const float4*>(&hstore[lane][4]);
            const float4 a2 = *reinterpret_cast<const float4*>(&hstore[lane][8]);
            const float4 a3 = *reinterpret_cast<const float4*>(&hstore[lane][12]);
            const float4 a4 = *reinterpret_cast<const float4*>(&hstore[lane][16]);
            float s = (((a0.x + a0.y) + (a0.z + a0.w)) +
                       ((a1.x + a1.y) + (a1.z + a1.w))) +
                      (((a2.x + a2.y) + (a2.z + a2.w)) +
                       ((a3.x + a3.y) + (a3.z + a3.w))) +
                      ((a4.x + a4.y) + (a4.z + a4.w));
            int t = tstart + b * 64 + lane;
            if (t >= 0 && t < n) out[t] = s + bo;  // coalesced
        }
        xgv = xgn; xpv = xpn;
    }
}

extern "C" void kernel_launch(void* const* d_in, const int* in_sizes, int n_in,
                              void* d_out, int out_size, void* d_ws, size_t ws_size,
                              hipStream_t stream) {
    const float* grad = (const float*)d_in[0];
    const float* par  = (const float*)d_in[1];
    const float* Wih0 = (const float*)d_in[2];
    const float* Whh0 = (const float*)d_in[3];
    const float* bih0 = (const float*)d_in[4];
    const float* bhh0 = (const float*)d_in[5];
    const float* Wih1 = (const float*)d_in[6];
    const float* Whh1 = (const float*)d_in[7];
    const float* bih1 = (const float*)d_in[8];
    const float* bhh1 = (const float*)d_in[9];
    const float* Wout = (const float*)d_in[10];
    const float* bout = (const float*)d_in[11];
    float* out = (float*)d_out;

    const int n = in_sizes[0];
    const int chunks = (n + CHUNK - 1) / CHUNK;   // 2048 for n=524288 -> 2 waves/SIMD

    lstm_opt_kernel<<<chunks, 64, 0, stream>>>(grad, par, Wih0, Whh0, bih0, bhh0,
                                               Wih1, Whh1, bih1, bhh1, Wout, bout,
                                               out, n);
}